// Round 5
// baseline (521.383 us; speedup 1.0000x reference)
//
#include <hip/hip_runtime.h>
#include <hip/hip_bf16.h>
#include <math.h>

typedef __attribute__((ext_vector_type(4))) float floatx4;
typedef __attribute__((ext_vector_type(16))) float floatx16;
typedef __attribute__((ext_vector_type(8))) __bf16 bf16x8;

__device__ __forceinline__ unsigned short f2bf(float f) {
    union { float f; unsigned int u; } v; v.f = f;
    unsigned int u = v.u;
    u += 0x7FFFu + ((u >> 16) & 1u);          // round-to-nearest-even
    return (unsigned short)(u >> 16);
}

__device__ __forceinline__ unsigned int pkbf(float a, float b) {
    return (unsigned int)f2bf(a) | ((unsigned int)f2bf(b) << 16);  // low16=a
}

// async global->LDS, 16B per lane; lds base must be wave-uniform
__device__ __forceinline__ void gl_lds16(const void* g, void* l) {
    __builtin_amdgcn_global_load_lds(
        (const __attribute__((address_space(1))) void*)g,
        (__attribute__((address_space(3))) void*)l, 16, 0, 0);
}

// ---------------------------------------------------------------- cast kernel
__global__ void cast_f32_bf16(const float* __restrict__ in,
                              unsigned short* __restrict__ out, int n) {
    int i = (blockIdx.x * blockDim.x + threadIdx.x) * 4;
    if (i + 4 <= n) {
        float4 f = *(const float4*)(in + i);
        ushort4 o;
        o.x = f2bf(f.x); o.y = f2bf(f.y); o.z = f2bf(f.z); o.w = f2bf(f.w);
        *(ushort4*)(out + i) = o;
    }
}

// ---------------------------------------------------------------- GEMM (NT)
// C[M,N] = A[M,K] * B[N,K]^T + bias[N]
// BM=256 x BN=128 tile, BK=64, 8 waves (2M x 4N, per-wave 128x32).
// 4-phase counted-vmcnt schedule (T1+T2+T3/T4+T5). LDS: 2 x 48KB = 96 KiB.
// (round-2 verified; unchanged)

#define VMCNT(n) asm volatile("s_waitcnt vmcnt(" #n ")" ::: "memory")
#define LGKM0()  asm volatile("s_waitcnt lgkmcnt(0)" ::: "memory")
#define BARF()   do { asm volatile("" ::: "memory"); __builtin_amdgcn_s_barrier(); \
                      asm volatile("" ::: "memory"); } while (0)

#define STAGE_A4(bsel, tt, h) do { \
    const unsigned short* _s = Ab + (size_t)((h) * 128 + rstage) * K + (tt) * 64 + scol; \
    char* _d = bufc + (bsel) * 49152 + (h) * 16384 + wid * 1024; \
    gl_lds16(_s, _d); \
    gl_lds16(_s + (size_t)64 * K, _d + 8192); \
} while (0)

#define STAGE_B4(bsel, tt, h) do { \
    const unsigned short* _s = Bb + (size_t)((h) * 64 + rstage) * K + (tt) * 64 + scol; \
    char* _d = bufc + (bsel) * 49152 + 32768 + (h) * 8192 + wid * 1024; \
    gl_lds16(_s, _d); \
} while (0)

#define STAGE_TILE(bsel, tt) do { \
    STAGE_A4(bsel, tt, 0); STAGE_A4(bsel, tt, 1); \
    STAGE_B4(bsel, tt, 0); STAGE_B4(bsel, tt, 1); \
} while (0)   /* 6 vm-instructions total */

#define RDA(base, ii, kse) (*(const bf16x8*)((base) + (ii) * 2048 + rdoffA + (kse)))
#define RDB(base, jj, kse) (*(const bf16x8*)((base) + (jj) * 2048 + rdoffB + (kse)))

#define MFMA_C(iofs) do { \
    __builtin_amdgcn_s_setprio(1); \
    _Pragma("unroll") \
    for (int ii = 0; ii < 4; ++ii) { \
        _Pragma("unroll") \
        for (int jj = 0; jj < 2; ++jj) { \
            acc[(iofs) + ii][jj] = __builtin_amdgcn_mfma_f32_16x16x32_bf16( \
                aF[((iofs) + ii) * 2 + 0], bL[jj * 2 + 0], acc[(iofs) + ii][jj], 0, 0, 0); \
            acc[(iofs) + ii][jj] = __builtin_amdgcn_mfma_f32_16x16x32_bf16( \
                aF[((iofs) + ii) * 2 + 1], bL[jj * 2 + 1], acc[(iofs) + ii][jj], 0, 0, 0); \
        } } \
    __builtin_amdgcn_s_setprio(0); \
} while (0)

template<int MODE>
__global__ __launch_bounds__(512, 2) void gemm4p(
    const unsigned short* __restrict__ A,
    const unsigned short* __restrict__ B,
    const float* __restrict__ bias,
    float* __restrict__ Cf,
    unsigned short* __restrict__ q_ws,
    unsigned short* __restrict__ k_ws,
    unsigned short* __restrict__ vT_ws,
    int M, int N, int K)
{
    extern __shared__ char ldsc[];
    char* const bufc = ldsc;

    const int nby = M >> 8;
    const int nwg = gridDim.x;
    const int qq = nwg >> 3;
    const int wg = (blockIdx.x & 7) * qq + (blockIdx.x >> 3);
    const int by = wg % nby, bx = wg / nby;
    const int m0 = by << 8, n0 = bx << 7;

    const int tid = threadIdx.x;
    const int lane = tid & 63, wid = tid >> 6;
    const int li = lane & 15, quad = lane >> 4;
    const int wr = wid >> 2, wc = wid & 3;

    const int rstage = tid >> 3;
    const int scol = (((tid & 7) ^ ((tid >> 3) & 7)) << 3);
    const unsigned short* Ab = A + (size_t)m0 * K;
    const unsigned short* Bb = B + (size_t)n0 * K;

    const int swz = (lane & 7) << 4;
    const int ks0 = ((quad << 4)     ) ^ swz;
    const int ks1 = ((quad << 4) + 64) ^ swz;
    const int rdoffA = li * 128;
    const int rdoffB = li * 128 + ((wc & 1) << 12);

    const char* rdA0 = bufc + wr * 16384;
    const char* rdB0 = bufc + 32768 + (wc >> 1) * 8192;
    const char* rdA1 = rdA0 + 49152;
    const char* rdB1 = rdB0 + 49152;

    floatx4 acc[8][2] = {};
    bf16x8 aF[16], bL[4];

    const int KTn = K >> 6;

    STAGE_TILE(0, 0);
    STAGE_TILE(1, 1);
    VMCNT(6);
    BARF();

    for (int t = 0; t < KTn; t += 2) {
        const bool pf = (t + 2 < KTn);

        #pragma unroll
        for (int ii = 0; ii < 8; ++ii) { aF[ii*2+0] = RDA(rdA0, ii, ks0); aF[ii*2+1] = RDA(rdA0, ii, ks1); }
        #pragma unroll
        for (int jj = 0; jj < 2; ++jj) { bL[jj*2+0] = RDB(rdB0, jj, ks0); bL[jj*2+1] = RDB(rdB0, jj, ks1); }
        BARF();
        MFMA_C(0);
        LGKM0();
        BARF();

        if (pf) STAGE_TILE(0, t + 2);
        BARF();
        MFMA_C(4);
        if (pf) { VMCNT(6); } else { VMCNT(0); }
        BARF();

        #pragma unroll
        for (int ii = 0; ii < 8; ++ii) { aF[ii*2+0] = RDA(rdA1, ii, ks0); aF[ii*2+1] = RDA(rdA1, ii, ks1); }
        #pragma unroll
        for (int jj = 0; jj < 2; ++jj) { bL[jj*2+0] = RDB(rdB1, jj, ks0); bL[jj*2+1] = RDB(rdB1, jj, ks1); }
        BARF();
        MFMA_C(0);
        LGKM0();
        BARF();

        if (pf) STAGE_TILE(1, t + 3);
        BARF();
        MFMA_C(4);
        if (pf) { VMCNT(6); } else { VMCNT(0); }
        BARF();
    }

    const int colb = wc * 32;
    const int rowb = wr * 128;
    if (MODE == 0) {
        #pragma unroll
        for (int i2 = 0; i2 < 8; ++i2)
            #pragma unroll
            for (int j2 = 0; j2 < 2; ++j2) {
                const int col = n0 + colb + j2 * 16 + li;
                const float bv = bias[col];
                #pragma unroll
                for (int r = 0; r < 4; ++r) {
                    const int row = m0 + rowb + i2 * 16 + quad * 4 + r;
                    Cf[(size_t)row * N + col] = acc[i2][j2][r] + bv;
                }
            }
    } else {
        const int which = bx >> 4;           // 0:q 1:k 2:vT
        const int hh = bx & 15;
        const int lbase = m0 & 2047;
        const size_t bh = (size_t)((m0 >> 11) * 16 + hh);
        if (which == 2) {
            unsigned short (*Lv)[264] = (unsigned short(*)[264])ldsc;
            #pragma unroll
            for (int i2 = 0; i2 < 8; ++i2)
                #pragma unroll
                for (int j2 = 0; j2 < 2; ++j2) {
                    const int col = colb + j2 * 16 + li;
                    const float bv = bias[n0 + col];
                    #pragma unroll
                    for (int r = 0; r < 4; ++r) {
                        const int row = rowb + i2 * 16 + quad * 4 + r;
                        Lv[col][row] = f2bf(acc[i2][j2][r] + bv);
                    }
                }
            __syncthreads();
            #pragma unroll
            for (int c = 0; c < 8; ++c) {
                int chunk = c * 512 + tid;
                int d = chunk >> 5;
                int ls = (chunk & 31) * 8;
                *(uint4*)(vT_ws + (bh * 128 + d) * 2048 + lbase + ls) =
                    *(const uint4*)&Lv[d][ls];
            }
        } else {
            unsigned short (*Lq)[136] = (unsigned short(*)[136])ldsc;
            #pragma unroll
            for (int i2 = 0; i2 < 8; ++i2)
                #pragma unroll
                for (int j2 = 0; j2 < 2; ++j2) {
                    const int col = colb + j2 * 16 + li;
                    const float bv = bias[n0 + col];
                    #pragma unroll
                    for (int r = 0; r < 4; ++r) {
                        const int row = rowb + i2 * 16 + quad * 4 + r;
                        Lq[row][col] = f2bf(acc[i2][j2][r] + bv);
                    }
                }
            __syncthreads();
            unsigned short* dst = which ? k_ws : q_ws;
            #pragma unroll
            for (int c = 0; c < 8; ++c) {
                int chunk = c * 512 + tid;
                int row = chunk >> 4;
                int dc = (chunk & 15) * 8;
                *(uint4*)(dst + (bh * 2048 + lbase + row) * (size_t)128 + dc) =
                    *(const uint4*)&Lq[row][dc];
            }
        }
    }
}

// ---------------------------------------------------------------- attention
// Round-4 counters: OccupancyPercent pinned at 12.6% with LDS 35KB + VGPR 84
// => GRID-limited (512 blocks = 2/CU), not resource-limited. Fix: QBLK=64,
// 4 waves/block with 2-way KEY split inside the block -> 1024 blocks,
// 4 blocks/CU resident (LDS 35,840 B), 16 waves/CU at start.
// Wave (wq,wk): q-rows qt*64+wq*32+[0,32), keys wk*32+[0,32) of each 64-key
// tile; per-wave running (m,l,O); one LDS flash-merge across wk at the end.
// Math per-tile is the verified round-4 kernel specialized to 32 keys.
__global__ __launch_bounds__(256, 4) void attn_kernel(
    const unsigned short* __restrict__ q_ws,
    const unsigned short* __restrict__ k_ws,
    const unsigned short* __restrict__ vT_ws,
    unsigned short* __restrict__ aout,
    const int* __restrict__ causal_ptr)
{
    // Ks [64][136] + Vs [128][72] = 35,840 B.
    // Epilogue reuse: Ep f32 [64][132] (33,792 B) + stats 1,024 B = 34,816 B.
    __shared__ unsigned short smem[64 * 136 + 128 * 72];
    unsigned short* const Ks = smem;
    unsigned short* const Vs = smem + 64 * 136;

    // same-bh blocks adjacent (K/V L2 locality); qt descending = LPT
    const int ord = blockIdx.x;
    const int bhid = ord >> 5;                 // 0..31
    const int qt = 31 - (ord & 31);            // 0..31, longest first
    const int b = bhid >> 4, h = bhid & 15;

    const int tid = threadIdx.x;
    const int lane = tid & 63, w = tid >> 6;   // 4 waves
    const int wq = w & 1, wk = w >> 1;         // q-half, key-half
    const int lq = lane & 31;
    const int half = lane >> 5;
    const size_t bh = (size_t)(b * 16 + h);
    const unsigned short* Qp = q_ws + bh * 2048 * 128;
    const unsigned short* Kp = k_ws + bh * 2048 * 128;
    const unsigned short* Vp = vT_ws + bh * 128 * 2048;
    const int causal = causal_ptr[0];
    const float scale = 0.08838834764831845f;  // 1/sqrt(128)

    // Q^T B-operand frags (persist)
    const int qg = qt * 64 + wq * 32 + lq;
    bf16x8 qf[8];
    #pragma unroll
    for (int s = 0; s < 8; ++s)
        qf[s] = *(const bf16x8*)(Qp + (size_t)qg * 128 + s * 16 + half * 8);

    floatx16 O[4] = {};
    float m_i = -INFINITY, l_i = 0.f;

    const int nkt = causal ? (qt + 1) : 32;    // 64-key tiles
    for (int kt = 0; kt < nkt; ++kt) {
        // stage K [64 keys][128 d] and V^T [128 d][64 keys]: 4+4 uint4/thread
        #pragma unroll
        for (int c = 0; c < 4; ++c) {
            int chunk = c * 256 + tid;         // 0..1023
            int krow = chunk >> 4;             // 0..63 (key)
            int kcc  = (chunk & 15) * 8;       // d col 0..120
            *(uint4*)(Ks + krow * 136 + kcc) =
                *(const uint4*)(Kp + (size_t)(kt * 64 + krow) * 128 + kcc);
            int vrow = chunk >> 3;             // 0..127 (d)
            int vcc  = (chunk & 7) * 8;        // key col 0..56
            *(uint4*)(Vs + vrow * 72 + vcc) =
                *(const uint4*)(Vp + (size_t)vrow * 2048 + kt * 64 + vcc);
        }
        __syncthreads();

        // S^T[key][q] for my 32-key half; A = K rows, B = Q^T
        floatx16 S = {};
        #pragma unroll
        for (int s = 0; s < 8; ++s) {
            bf16x8 kf = *(const bf16x8*)(Ks + (wk * 32 + lq) * 136 + s * 16 + half * 8);
            S = __builtin_amdgcn_mfma_f32_32x32x16_bf16(kf, qf[s], S, 0, 0, 0);
        }

        // scale + causal mask; stats lane-local (col of S^T = q)
        const bool diag = causal && (kt == qt);
        float mx = -INFINITY;
        #pragma unroll
        for (int r = 0; r < 16; ++r) {
            float sv = S[r] * scale;
            if (diag) {
                int key = kt * 64 + wk * 32 + (r & 3) + 8 * (r >> 2) + 4 * half;
                if (key > qg) sv = -INFINITY;
            }
            S[r] = sv;
            mx = fmaxf(mx, sv);
        }
        mx = fmaxf(mx, __shfl_xor(mx, 32, 64));
        float m_new = fmaxf(m_i, mx);
        float m_use = (m_new == -INFINITY) ? 0.f : m_new;
        float alpha = __expf(m_i - m_use);

        float rs = 0.f;
        #pragma unroll
        for (int r = 0; r < 16; ++r) {
            float p = __expf(S[r] - m_use);
            S[r] = p;
            rs += p;
        }
        rs += __shfl_xor(rs, 32, 64);
        l_i = l_i * alpha + rs;
        m_i = m_new;
        #pragma unroll
        for (int dt = 0; dt < 4; ++dt)
            #pragma unroll
            for (int r = 0; r < 16; ++r)
                O[dt][r] *= alpha;

        // P^T -> 2 B-operand frags via register half-swap
        bf16x8 pfr[2];
        #pragma unroll
        for (int h2 = 0; h2 < 2; ++h2) {
            int base = 8 * h2;
            unsigned int pk0 = pkbf(S[base + 0], S[base + 1]);
            unsigned int pk1 = pkbf(S[base + 2], S[base + 3]);
            unsigned int pk2 = pkbf(S[base + 4], S[base + 5]);
            unsigned int pk3 = pkbf(S[base + 6], S[base + 7]);
            unsigned int x0 = __shfl_xor((int)pk0, 32, 64);
            unsigned int x1 = __shfl_xor((int)pk1, 32, 64);
            unsigned int x2 = __shfl_xor((int)pk2, 32, 64);
            unsigned int x3 = __shfl_xor((int)pk3, 32, 64);
            union { unsigned int u[4]; bf16x8 v; } fr;
            fr.u[0] = half ? x2 : pk0;
            fr.u[1] = half ? x3 : pk1;
            fr.u[2] = half ? pk2 : x0;
            fr.u[3] = half ? pk3 : x1;
            pfr[h2] = fr.v;
        }

        // O^T[d][q] += V^T * P^T over my 32-key half
        #pragma unroll
        for (int dt = 0; dt < 4; ++dt)
            #pragma unroll
            for (int s = 0; s < 2; ++s) {
                bf16x8 vf = *(const bf16x8*)(Vs + (dt * 32 + lq) * 72 + wk * 32 + s * 16 + half * 8);
                O[dt] = __builtin_amdgcn_mfma_f32_32x32x16_bf16(vf, pfr[s], O[dt], 0, 0, 0);
            }
        __syncthreads();   // before next tile restages K/V
    }

    // ---- cross-key-half flash merge (in LDS, no extra HBM)
    float* const Ep  = (float*)smem;                 // [64][132]
    float* const stm = (float*)smem + 64 * 132;      // [2][2][32] running max
    float* const stl = stm + 128;                    // [2][2][32] running sum
    if (lane < 32) {
        stm[(wk * 2 + wq) * 32 + lq] = m_i;
        stl[(wk * 2 + wq) * 32 + lq] = l_i;
    }
    __syncthreads();
    const float m_o = stm[((wk ^ 1) * 2 + wq) * 32 + lq];
    const float l_o = stl[((wk ^ 1) * 2 + wq) * 32 + lq];
    const float M = fmaxf(m_i, m_o);
    const float sc  = __expf(m_i - M);
    const float l_f = l_i * sc + l_o * __expf(m_o - M);
    const float f = sc / l_f;                        // fold normalize into merge

    if (wk == 0) {
        #pragma unroll
        for (int dt = 0; dt < 4; ++dt)
            #pragma unroll
            for (int r = 0; r < 16; ++r) {
                int d = dt * 32 + (r & 3) + 8 * (r >> 2) + 4 * half;
                Ep[(wq * 32 + lq) * 132 + d] = O[dt][r] * f;
            }
    }
    __syncthreads();
    if (wk == 1) {
        #pragma unroll
        for (int dt = 0; dt < 4; ++dt)
            #pragma unroll
            for (int r = 0; r < 16; ++r) {
                int d = dt * 32 + (r & 3) + 8 * (r >> 2) + 4 * half;
                Ep[(wq * 32 + lq) * 132 + d] += O[dt][r] * f;
            }
    }
    __syncthreads();

    // cast + coalesced store: 64 rows x 128 d
    #pragma unroll
    for (int c = 0; c < 4; ++c) {
        int chunk = c * 256 + tid;               // 0..1023
        int row = chunk >> 4;                    // 0..63
        int dc = (chunk & 15) * 8;               // 0..120
        const float* ep = Ep + row * 132 + dc;
        ushort4 o0, o1;
        o0.x = f2bf(ep[0]); o0.y = f2bf(ep[1]); o0.z = f2bf(ep[2]); o0.w = f2bf(ep[3]);
        o1.x = f2bf(ep[4]); o1.y = f2bf(ep[5]); o1.z = f2bf(ep[6]); o1.w = f2bf(ep[7]);
        unsigned short* dst = aout + ((size_t)b * 2048 + qt * 64 + row) * 2048 + h * 128 + dc;
        *(ushort4*)dst = o0;
        *(ushort4*)(dst + 4) = o1;
    }
}

// ---------------------------------------------------------------- launch
extern "C" void kernel_launch(void* const* d_in, const int* in_sizes, int n_in,
                              void* d_out, int out_size, void* d_ws, size_t ws_size,
                              hipStream_t stream) {
    const float* x     = (const float*)d_in[0];
    const float* w_in  = (const float*)d_in[1];
    const float* b_in  = (const float*)d_in[2];
    const float* w_out = (const float*)d_in[3];
    const float* b_out = (const float*)d_in[4];
    const int* causal  = (const int*)d_in[5];

    char* ws = (char*)d_ws;
    unsigned short* xb    = (unsigned short*)ws; ws += (size_t)4096 * 2048 * 2;
    unsigned short* wb    = (unsigned short*)ws; ws += (size_t)6144 * 2048 * 2;
    unsigned short* wob   = (unsigned short*)ws; ws += (size_t)2048 * 2048 * 2;
    unsigned short* q_ws  = (unsigned short*)ws; ws += (size_t)32 * 2048 * 128 * 2;
    unsigned short* k_ws  = (unsigned short*)ws; ws += (size_t)32 * 2048 * 128 * 2;
    unsigned short* vT_ws = (unsigned short*)ws; ws += (size_t)32 * 2048 * 128 * 2;
    unsigned short* aout  = (unsigned short*)ws; ws += (size_t)4096 * 2048 * 2;

    static int once = []() {
        auto* f0 = gemm4p<0>;
        auto* f1 = gemm4p<1>;
        hipFuncSetAttribute((const void*)f0,
            hipFuncAttributeMaxDynamicSharedMemorySize, 98304);
        hipFuncSetAttribute((const void*)f1,
            hipFuncAttributeMaxDynamicSharedMemorySize, 98304);
        return 0;
    }();
    (void)once;

    cast_f32_bf16<<<8192, 256, 0, stream>>>(x, xb, 4096 * 2048);
    cast_f32_bf16<<<12288, 256, 0, stream>>>(w_in, wb, 6144 * 2048);
    cast_f32_bf16<<<4096, 256, 0, stream>>>(w_out, wob, 2048 * 2048);

    // QKV: M=4096, N=6144 -> grid 16*48 = 768 = 3 full rounds
    gemm4p<1><<<768, 512, 98304, stream>>>(
        xb, wb, b_in, nullptr, q_ws, k_ws, vT_ws, 4096, 6144, 2048);

    // attn: 32 bh x 32 qtiles = 1024 blocks, 4 blocks/CU resident
    attn_kernel<<<1024, 256, 0, stream>>>(
        q_ws, k_ws, vT_ws, aout, causal);

    // out-proj: M=4096, N=2048 -> grid 16*16 = 256 = 1 full round
    gemm4p<0><<<256, 512, 98304, stream>>>(
        aout, wob, b_out, (float*)d_out, nullptr, nullptr, nullptr,
        4096, 2048, 2048);
}

// Round 6
// 452.060 us; speedup vs baseline: 1.1533x; 1.1533x over previous
//
#include <hip/hip_runtime.h>
#include <hip/hip_bf16.h>
#include <math.h>

typedef __attribute__((ext_vector_type(4))) float floatx4;
typedef __attribute__((ext_vector_type(16))) float floatx16;
typedef __attribute__((ext_vector_type(8))) __bf16 bf16x8;

__device__ __forceinline__ unsigned short f2bf(float f) {
    union { float f; unsigned int u; } v; v.f = f;
    unsigned int u = v.u;
    u += 0x7FFFu + ((u >> 16) & 1u);          // round-to-nearest-even
    return (unsigned short)(u >> 16);
}

__device__ __forceinline__ unsigned int pkbf(float a, float b) {
    return (unsigned int)f2bf(a) | ((unsigned int)f2bf(b) << 16);  // low16=a
}

// async global->LDS, 16B per lane; lds base must be wave-uniform
__device__ __forceinline__ void gl_lds16(const void* g, void* l) {
    __builtin_amdgcn_global_load_lds(
        (const __attribute__((address_space(1))) void*)g,
        (__attribute__((address_space(3))) void*)l, 16, 0, 0);
}

// ---------------------------------------------------------------- cast kernel
__global__ void cast_f32_bf16(const float* __restrict__ in,
                              unsigned short* __restrict__ out, int n) {
    int i = (blockIdx.x * blockDim.x + threadIdx.x) * 4;
    if (i + 4 <= n) {
        float4 f = *(const float4*)(in + i);
        ushort4 o;
        o.x = f2bf(f.x); o.y = f2bf(f.y); o.z = f2bf(f.z); o.w = f2bf(f.w);
        *(ushort4*)(out + i) = o;
    }
}

// ---------------------------------------------------------------- GEMM (NT)
// C[M,N] = A[M,K] * B[N,K]^T + bias[N]
// BM=256 x BN=128 tile, BK=64, 8 waves (2M x 4N, per-wave 128x32).
// 4-phase counted-vmcnt schedule (T1+T2+T3/T4+T5). LDS: 2 x 48KB = 96 KiB.
// (round-2 verified; unchanged)

#define VMCNT(n) asm volatile("s_waitcnt vmcnt(" #n ")" ::: "memory")
#define LGKM0()  asm volatile("s_waitcnt lgkmcnt(0)" ::: "memory")
#define BARF()   do { asm volatile("" ::: "memory"); __builtin_amdgcn_s_barrier(); \
                      asm volatile("" ::: "memory"); } while (0)

#define STAGE_A4(bsel, tt, h) do { \
    const unsigned short* _s = Ab + (size_t)((h) * 128 + rstage) * K + (tt) * 64 + scol; \
    char* _d = bufc + (bsel) * 49152 + (h) * 16384 + wid * 1024; \
    gl_lds16(_s, _d); \
    gl_lds16(_s + (size_t)64 * K, _d + 8192); \
} while (0)

#define STAGE_B4(bsel, tt, h) do { \
    const unsigned short* _s = Bb + (size_t)((h) * 64 + rstage) * K + (tt) * 64 + scol; \
    char* _d = bufc + (bsel) * 49152 + 32768 + (h) * 8192 + wid * 1024; \
    gl_lds16(_s, _d); \
} while (0)

#define STAGE_TILE(bsel, tt) do { \
    STAGE_A4(bsel, tt, 0); STAGE_A4(bsel, tt, 1); \
    STAGE_B4(bsel, tt, 0); STAGE_B4(bsel, tt, 1); \
} while (0)   /* 6 vm-instructions total */

#define RDA(base, ii, kse) (*(const bf16x8*)((base) + (ii) * 2048 + rdoffA + (kse)))
#define RDB(base, jj, kse) (*(const bf16x8*)((base) + (jj) * 2048 + rdoffB + (kse)))

#define MFMA_C(iofs) do { \
    __builtin_amdgcn_s_setprio(1); \
    _Pragma("unroll") \
    for (int ii = 0; ii < 4; ++ii) { \
        _Pragma("unroll") \
        for (int jj = 0; jj < 2; ++jj) { \
            acc[(iofs) + ii][jj] = __builtin_amdgcn_mfma_f32_16x16x32_bf16( \
                aF[((iofs) + ii) * 2 + 0], bL[jj * 2 + 0], acc[(iofs) + ii][jj], 0, 0, 0); \
            acc[(iofs) + ii][jj] = __builtin_amdgcn_mfma_f32_16x16x32_bf16( \
                aF[((iofs) + ii) * 2 + 1], bL[jj * 2 + 1], acc[(iofs) + ii][jj], 0, 0, 0); \
        } } \
    __builtin_amdgcn_s_setprio(0); \
} while (0)

template<int MODE>
__global__ __launch_bounds__(512, 2) void gemm4p(
    const unsigned short* __restrict__ A,
    const unsigned short* __restrict__ B,
    const float* __restrict__ bias,
    float* __restrict__ Cf,
    unsigned short* __restrict__ q_ws,
    unsigned short* __restrict__ k_ws,
    unsigned short* __restrict__ vT_ws,
    int M, int N, int K)
{
    extern __shared__ char ldsc[];
    char* const bufc = ldsc;

    const int nby = M >> 8;
    const int nwg = gridDim.x;
    const int qq = nwg >> 3;
    const int wg = (blockIdx.x & 7) * qq + (blockIdx.x >> 3);
    const int by = wg % nby, bx = wg / nby;
    const int m0 = by << 8, n0 = bx << 7;

    const int tid = threadIdx.x;
    const int lane = tid & 63, wid = tid >> 6;
    const int li = lane & 15, quad = lane >> 4;
    const int wr = wid >> 2, wc = wid & 3;

    const int rstage = tid >> 3;
    const int scol = (((tid & 7) ^ ((tid >> 3) & 7)) << 3);
    const unsigned short* Ab = A + (size_t)m0 * K;
    const unsigned short* Bb = B + (size_t)n0 * K;

    const int swz = (lane & 7) << 4;
    const int ks0 = ((quad << 4)     ) ^ swz;
    const int ks1 = ((quad << 4) + 64) ^ swz;
    const int rdoffA = li * 128;
    const int rdoffB = li * 128 + ((wc & 1) << 12);

    const char* rdA0 = bufc + wr * 16384;
    const char* rdB0 = bufc + 32768 + (wc >> 1) * 8192;
    const char* rdA1 = rdA0 + 49152;
    const char* rdB1 = rdB0 + 49152;

    floatx4 acc[8][2] = {};
    bf16x8 aF[16], bL[4];

    const int KTn = K >> 6;

    STAGE_TILE(0, 0);
    STAGE_TILE(1, 1);
    VMCNT(6);
    BARF();

    for (int t = 0; t < KTn; t += 2) {
        const bool pf = (t + 2 < KTn);

        #pragma unroll
        for (int ii = 0; ii < 8; ++ii) { aF[ii*2+0] = RDA(rdA0, ii, ks0); aF[ii*2+1] = RDA(rdA0, ii, ks1); }
        #pragma unroll
        for (int jj = 0; jj < 2; ++jj) { bL[jj*2+0] = RDB(rdB0, jj, ks0); bL[jj*2+1] = RDB(rdB0, jj, ks1); }
        BARF();
        MFMA_C(0);
        LGKM0();
        BARF();

        if (pf) STAGE_TILE(0, t + 2);
        BARF();
        MFMA_C(4);
        if (pf) { VMCNT(6); } else { VMCNT(0); }
        BARF();

        #pragma unroll
        for (int ii = 0; ii < 8; ++ii) { aF[ii*2+0] = RDA(rdA1, ii, ks0); aF[ii*2+1] = RDA(rdA1, ii, ks1); }
        #pragma unroll
        for (int jj = 0; jj < 2; ++jj) { bL[jj*2+0] = RDB(rdB1, jj, ks0); bL[jj*2+1] = RDB(rdB1, jj, ks1); }
        BARF();
        MFMA_C(0);
        LGKM0();
        BARF();

        if (pf) STAGE_TILE(1, t + 3);
        BARF();
        MFMA_C(4);
        if (pf) { VMCNT(6); } else { VMCNT(0); }
        BARF();
    }

    const int colb = wc * 32;
    const int rowb = wr * 128;
    if (MODE == 0) {
        #pragma unroll
        for (int i2 = 0; i2 < 8; ++i2)
            #pragma unroll
            for (int j2 = 0; j2 < 2; ++j2) {
                const int col = n0 + colb + j2 * 16 + li;
                const float bv = bias[col];
                #pragma unroll
                for (int r = 0; r < 4; ++r) {
                    const int row = m0 + rowb + i2 * 16 + quad * 4 + r;
                    Cf[(size_t)row * N + col] = acc[i2][j2][r] + bv;
                }
            }
    } else {
        const int which = bx >> 4;           // 0:q 1:k 2:vT
        const int hh = bx & 15;
        const int lbase = m0 & 2047;
        const size_t bh = (size_t)((m0 >> 11) * 16 + hh);
        if (which == 2) {
            unsigned short (*Lv)[264] = (unsigned short(*)[264])ldsc;
            #pragma unroll
            for (int i2 = 0; i2 < 8; ++i2)
                #pragma unroll
                for (int j2 = 0; j2 < 2; ++j2) {
                    const int col = colb + j2 * 16 + li;
                    const float bv = bias[n0 + col];
                    #pragma unroll
                    for (int r = 0; r < 4; ++r) {
                        const int row = rowb + i2 * 16 + quad * 4 + r;
                        Lv[col][row] = f2bf(acc[i2][j2][r] + bv);
                    }
                }
            __syncthreads();
            #pragma unroll
            for (int c = 0; c < 8; ++c) {
                int chunk = c * 512 + tid;
                int d = chunk >> 5;
                int ls = (chunk & 31) * 8;
                *(uint4*)(vT_ws + (bh * 128 + d) * 2048 + lbase + ls) =
                    *(const uint4*)&Lv[d][ls];
            }
        } else {
            unsigned short (*Lq)[136] = (unsigned short(*)[136])ldsc;
            #pragma unroll
            for (int i2 = 0; i2 < 8; ++i2)
                #pragma unroll
                for (int j2 = 0; j2 < 2; ++j2) {
                    const int col = colb + j2 * 16 + li;
                    const float bv = bias[n0 + col];
                    #pragma unroll
                    for (int r = 0; r < 4; ++r) {
                        const int row = rowb + i2 * 16 + quad * 4 + r;
                        Lq[row][col] = f2bf(acc[i2][j2][r] + bv);
                    }
                }
            __syncthreads();
            unsigned short* dst = which ? k_ws : q_ws;
            #pragma unroll
            for (int c = 0; c < 8; ++c) {
                int chunk = c * 512 + tid;
                int row = chunk >> 4;
                int dc = (chunk & 15) * 8;
                *(uint4*)(dst + (bh * 2048 + lbase + row) * (size_t)128 + dc) =
                    *(const uint4*)&Lq[row][dc];
            }
        }
    }
}

// ---------------------------------------------------------------- attention
// Back to the BEST-measured structure (R0/R2 baseline, ~135 us: QBLK=128,
// KVBLK=128, 4 waves, 512 blocks, balanced pairing) + ONE change: LDS
// double-buffer with full-tile latency coverage. Next-tile K/V global loads
// are issued into registers BEFORE QK^T of the current tile (latency ~600cy
// L3 hides under ~2000cy of QK+softmax+PV), committed to the other LDS
// buffer after compute; register dependence inserts the vmcnt wait.
// LDS: 2 x 69,632 = 139,264 B dynamic -> 1 block/CU (locality preserved,
// R5 showed occupancy without locality is a loss: FETCH 29->252 MB).
__global__ __launch_bounds__(256, 1) void attn_kernel(
    const unsigned short* __restrict__ q_ws,
    const unsigned short* __restrict__ k_ws,
    const unsigned short* __restrict__ vT_ws,
    unsigned short* __restrict__ aout,
    const int* __restrict__ causal_ptr)
{
    extern __shared__ char asmem[];
    unsigned short* const S0 = (unsigned short*)asmem;
    // buffer b (b=0,1): K at S0 + b*34816 ([128][136]), V at +17408

    // balanced mapping: blocks c and c+256 sum to 17 tile-computes
    const int ord = blockIdx.x;
    int qt, bhid;
    if (ord < 256) { qt = ord >> 5;              bhid = ord & 31; }
    else           { qt = 15 - ((ord - 256) >> 5); bhid = ord & 31; }
    const int b = bhid >> 4, h = bhid & 15;

    const int tid = threadIdx.x;
    const int lane = tid & 63, w = tid >> 6;       // 4 waves
    const int lq = lane & 31;                      // q-col / row-in-tile
    const int half = lane >> 5;
    const size_t bh = (size_t)(b * 16 + h);
    const unsigned short* Qp = q_ws + bh * 2048 * 128;
    const unsigned short* Kp = k_ws + bh * 2048 * 128;
    const unsigned short* Vp = vT_ws + bh * 128 * 2048;
    const int causal = causal_ptr[0];
    const float scale = 0.08838834764831845f;      // 1/sqrt(128)

    // per-thread staging coords: chunk = c*256+tid -> row, 16B col
    const int srow = tid >> 4;                     // + c*16
    const int scc  = (tid & 15) * 8;

    // Q^T B-operand frags (persist): qf[s][j] = Q[qg][16s + 8*half + j]
    const int qg = qt * 128 + w * 32 + lq;
    bf16x8 qf[8];
    #pragma unroll
    for (int s = 0; s < 8; ++s)
        qf[s] = *(const bf16x8*)(Qp + (size_t)qg * 128 + s * 16 + half * 8);

    floatx16 O[4] = {};
    float m_i = -INFINITY, l_i = 0.f;

    uint4 kr[8], vr[8];

    // prologue: load + commit tile 0 into buf0
    #pragma unroll
    for (int c = 0; c < 8; ++c) {
        int row = c * 16 + srow;
        kr[c] = *(const uint4*)(Kp + (size_t)row * 128 + scc);
        vr[c] = *(const uint4*)(Vp + (size_t)row * 2048 + scc);
    }
    #pragma unroll
    for (int c = 0; c < 8; ++c) {
        int row = c * 16 + srow;
        *(uint4*)(S0 + row * 136 + scc) = kr[c];
        *(uint4*)(S0 + 17408 + row * 136 + scc) = vr[c];
    }
    __syncthreads();

    const int myEnd = causal ? qt : 15;
    for (int kt = 0; kt <= myEnd; ++kt) {
        unsigned short* const Ksc = S0 + (kt & 1) * 34816;
        unsigned short* const Vsc = Ksc + 17408;
        const bool more = (kt < myEnd);

        // issue next tile's loads FIRST: latency hides under this tile's work
        if (more) {
            #pragma unroll
            for (int c = 0; c < 8; ++c) {
                int row = c * 16 + srow;
                kr[c] = *(const uint4*)(Kp + (size_t)((kt + 1) * 128 + row) * 128 + scc);
                vr[c] = *(const uint4*)(Vp + (size_t)row * 2048 + (kt + 1) * 128 + scc);
            }
        }

        // S^T[key][q]: 4 key-groups of 32; A = K rows, B = Q^T
        floatx16 S[4] = {};
        #pragma unroll
        for (int ct = 0; ct < 4; ++ct)
            #pragma unroll
            for (int s = 0; s < 8; ++s) {
                bf16x8 kf = *(const bf16x8*)(Ksc + (ct * 32 + lq) * 136 + s * 16 + half * 8);
                S[ct] = __builtin_amdgcn_mfma_f32_32x32x16_bf16(kf, qf[s], S[ct], 0, 0, 0);
            }

        // scale + causal mask; row stats are LANE-LOCAL (col of S^T = q)
        const bool diag = causal && (kt == qt);
        float mx = -INFINITY;
        #pragma unroll
        for (int ct = 0; ct < 4; ++ct)
            #pragma unroll
            for (int r = 0; r < 16; ++r) {
                float sv = S[ct][r] * scale;
                if (diag) {
                    int key = 32 * ct + (r & 3) + 8 * (r >> 2) + 4 * half;
                    if (kt * 128 + key > qg) sv = -INFINITY;
                }
                S[ct][r] = sv;
                mx = fmaxf(mx, sv);
            }
        mx = fmaxf(mx, __shfl_xor(mx, 32, 64));   // combine key-halves
        float m_new = fmaxf(m_i, mx);
        float m_use = (m_new == -INFINITY) ? 0.f : m_new;
        float alpha = __expf(m_i - m_use);

        float rs = 0.f;
        #pragma unroll
        for (int ct = 0; ct < 4; ++ct)
            #pragma unroll
            for (int r = 0; r < 16; ++r) {
                float p = __expf(S[ct][r] - m_use);
                S[ct][r] = p;
                rs += p;
            }
        rs += __shfl_xor(rs, 32, 64);
        l_i = l_i * alpha + rs;
        m_i = m_new;
        #pragma unroll
        for (int dt = 0; dt < 4; ++dt)
            #pragma unroll
            for (int r = 0; r < 16; ++r)
                O[dt][r] *= alpha;

        // P^T -> B-operand frags via register half-swap (no LDS round-trip)
        bf16x8 pfr[8];
        #pragma unroll
        for (int ct = 0; ct < 4; ++ct)
            #pragma unroll
            for (int h2 = 0; h2 < 2; ++h2) {
                int base = 8 * h2;
                unsigned int pk0 = pkbf(S[ct][base + 0], S[ct][base + 1]);
                unsigned int pk1 = pkbf(S[ct][base + 2], S[ct][base + 3]);
                unsigned int pk2 = pkbf(S[ct][base + 4], S[ct][base + 5]);
                unsigned int pk3 = pkbf(S[ct][base + 6], S[ct][base + 7]);
                unsigned int x0 = __shfl_xor((int)pk0, 32, 64);
                unsigned int x1 = __shfl_xor((int)pk1, 32, 64);
                unsigned int x2 = __shfl_xor((int)pk2, 32, 64);
                unsigned int x3 = __shfl_xor((int)pk3, 32, 64);
                union { unsigned int u[4]; bf16x8 v; } fr;
                fr.u[0] = half ? x2 : pk0;
                fr.u[1] = half ? x3 : pk1;
                fr.u[2] = half ? pk2 : x0;
                fr.u[3] = half ? pk3 : x1;
                pfr[ct * 2 + h2] = fr.v;
            }

        // O^T[d][q] += V^T * P^T; A = V^T rows (d), B = pfr
        #pragma unroll
        for (int dt = 0; dt < 4; ++dt)
            #pragma unroll
            for (int s = 0; s < 8; ++s) {
                bf16x8 vf = *(const bf16x8*)(Vsc + (dt * 32 + lq) * 136 + s * 16 + half * 8);
                O[dt] = __builtin_amdgcn_mfma_f32_32x32x16_bf16(vf, pfr[s], O[dt], 0, 0, 0);
            }

        // commit next tile to the OTHER buffer (nobody reads it this tile;
        // the kr/vr uses force the vmcnt wait here, after compute)
        if (more) {
            unsigned short* const Kn = S0 + ((kt + 1) & 1) * 34816;
            #pragma unroll
            for (int c = 0; c < 8; ++c) {
                int row = c * 16 + srow;
                *(uint4*)(Kn + row * 136 + scc) = kr[c];
                *(uint4*)(Kn + 17408 + row * 136 + scc) = vr[c];
            }
        }
        __syncthreads();   // commit visible; all reads of buf[kt&1] done
    }

    // epilogue: normalize, transpose O^T->[q][d] via buf0 region, store
    unsigned short* const Ep = S0;
    const float invl = 1.0f / l_i;
    #pragma unroll
    for (int dt = 0; dt < 4; ++dt)
        #pragma unroll
        for (int g = 0; g < 4; ++g) {
            int dbase = dt * 32 + g * 8 + half * 4;
            ushort4 o4;
            o4.x = f2bf(O[dt][g * 4 + 0] * invl);
            o4.y = f2bf(O[dt][g * 4 + 1] * invl);
            o4.z = f2bf(O[dt][g * 4 + 2] * invl);
            o4.w = f2bf(O[dt][g * 4 + 3] * invl);
            *(ushort4*)(Ep + (w * 32 + lq) * 136 + dbase) = o4;
        }
    __syncthreads();
    #pragma unroll
    for (int c = 0; c < 8; ++c) {
        int chunk = c * 256 + tid;                // 0..2047
        int row = chunk >> 4;                     // 0..127 (q within tile)
        int dc = (chunk & 15) * 8;
        uint4 v = *(const uint4*)(Ep + row * 136 + dc);
        *(uint4*)(aout + ((size_t)b * 2048 + qt * 128 + row) * 2048 + h * 128 + dc) = v;
    }
}

// ---------------------------------------------------------------- launch
extern "C" void kernel_launch(void* const* d_in, const int* in_sizes, int n_in,
                              void* d_out, int out_size, void* d_ws, size_t ws_size,
                              hipStream_t stream) {
    const float* x     = (const float*)d_in[0];
    const float* w_in  = (const float*)d_in[1];
    const float* b_in  = (const float*)d_in[2];
    const float* w_out = (const float*)d_in[3];
    const float* b_out = (const float*)d_in[4];
    const int* causal  = (const int*)d_in[5];

    char* ws = (char*)d_ws;
    unsigned short* xb    = (unsigned short*)ws; ws += (size_t)4096 * 2048 * 2;
    unsigned short* wb    = (unsigned short*)ws; ws += (size_t)6144 * 2048 * 2;
    unsigned short* wob   = (unsigned short*)ws; ws += (size_t)2048 * 2048 * 2;
    unsigned short* q_ws  = (unsigned short*)ws; ws += (size_t)32 * 2048 * 128 * 2;
    unsigned short* k_ws  = (unsigned short*)ws; ws += (size_t)32 * 2048 * 128 * 2;
    unsigned short* vT_ws = (unsigned short*)ws; ws += (size_t)32 * 2048 * 128 * 2;
    unsigned short* aout  = (unsigned short*)ws; ws += (size_t)4096 * 2048 * 2;

    static int once = []() {
        auto* f0 = gemm4p<0>;
        auto* f1 = gemm4p<1>;
        hipFuncSetAttribute((const void*)f0,
            hipFuncAttributeMaxDynamicSharedMemorySize, 98304);
        hipFuncSetAttribute((const void*)f1,
            hipFuncAttributeMaxDynamicSharedMemorySize, 98304);
        hipFuncSetAttribute((const void*)attn_kernel,
            hipFuncAttributeMaxDynamicSharedMemorySize, 139264);
        return 0;
    }();
    (void)once;

    cast_f32_bf16<<<8192, 256, 0, stream>>>(x, xb, 4096 * 2048);
    cast_f32_bf16<<<12288, 256, 0, stream>>>(w_in, wb, 6144 * 2048);
    cast_f32_bf16<<<4096, 256, 0, stream>>>(w_out, wob, 2048 * 2048);

    // QKV: M=4096, N=6144 -> grid 16*48 = 768 = 3 full rounds
    gemm4p<1><<<768, 512, 98304, stream>>>(
        xb, wb, b_in, nullptr, q_ws, k_ws, vT_ws, 4096, 6144, 2048);

    // attn: 512 blocks (balanced pairing), 139,264 B dynamic LDS (dbuf)
    attn_kernel<<<512, 256, 139264, stream>>>(
        q_ws, k_ws, vT_ws, aout, causal);

    // out-proj: M=4096, N=2048 -> grid 16*16 = 256 = 1 full round
    gemm4p<0><<<256, 512, 98304, stream>>>(
        aout, wob, b_out, (float*)d_out, nullptr, nullptr, nullptr,
        4096, 2048, 2048);
}

// Round 7
// 390.450 us; speedup vs baseline: 1.3353x; 1.1578x over previous
//
#include <hip/hip_runtime.h>
#include <hip/hip_bf16.h>
#include <math.h>

typedef __attribute__((ext_vector_type(4))) float floatx4;
typedef __attribute__((ext_vector_type(16))) float floatx16;
typedef __attribute__((ext_vector_type(8))) __bf16 bf16x8;

__device__ __forceinline__ unsigned short f2bf(float f) {
    union { float f; unsigned int u; } v; v.f = f;
    unsigned int u = v.u;
    u += 0x7FFFu + ((u >> 16) & 1u);          // round-to-nearest-even
    return (unsigned short)(u >> 16);
}

__device__ __forceinline__ unsigned int pkbf(float a, float b) {
    return (unsigned int)f2bf(a) | ((unsigned int)f2bf(b) << 16);  // low16=a
}

// async global->LDS, 16B per lane; lds dest is WAVE-uniform base (+lane*16 by HW)
__device__ __forceinline__ void gl_lds16(const void* g, void* l) {
    __builtin_amdgcn_global_load_lds(
        (const __attribute__((address_space(1))) void*)g,
        (__attribute__((address_space(3))) void*)l, 16, 0, 0);
}

// ---------------------------------------------------------------- cast kernel
__global__ void cast_f32_bf16(const float* __restrict__ in,
                              unsigned short* __restrict__ out, int n) {
    int i = (blockIdx.x * blockDim.x + threadIdx.x) * 4;
    if (i + 4 <= n) {
        float4 f = *(const float4*)(in + i);
        ushort4 o;
        o.x = f2bf(f.x); o.y = f2bf(f.y); o.z = f2bf(f.z); o.w = f2bf(f.w);
        *(ushort4*)(out + i) = o;
    }
}

// ---------------------------------------------------------------- GEMM (NT)
// (round-2 verified; unchanged)

#define VMCNT(n) asm volatile("s_waitcnt vmcnt(" #n ")" ::: "memory")
#define LGKM0()  asm volatile("s_waitcnt lgkmcnt(0)" ::: "memory")
#define BARF()   do { asm volatile("" ::: "memory"); __builtin_amdgcn_s_barrier(); \
                      asm volatile("" ::: "memory"); } while (0)

#define STAGE_A4(bsel, tt, h) do { \
    const unsigned short* _s = Ab + (size_t)((h) * 128 + rstage) * K + (tt) * 64 + scol; \
    char* _d = bufc + (bsel) * 49152 + (h) * 16384 + wid * 1024; \
    gl_lds16(_s, _d); \
    gl_lds16(_s + (size_t)64 * K, _d + 8192); \
} while (0)

#define STAGE_B4(bsel, tt, h) do { \
    const unsigned short* _s = Bb + (size_t)((h) * 64 + rstage) * K + (tt) * 64 + scol; \
    char* _d = bufc + (bsel) * 49152 + 32768 + (h) * 8192 + wid * 1024; \
    gl_lds16(_s, _d); \
} while (0)

#define STAGE_TILE(bsel, tt) do { \
    STAGE_A4(bsel, tt, 0); STAGE_A4(bsel, tt, 1); \
    STAGE_B4(bsel, tt, 0); STAGE_B4(bsel, tt, 1); \
} while (0)   /* 6 vm-instructions total */

#define RDA(base, ii, kse) (*(const bf16x8*)((base) + (ii) * 2048 + rdoffA + (kse)))
#define RDB(base, jj, kse) (*(const bf16x8*)((base) + (jj) * 2048 + rdoffB + (kse)))

#define MFMA_C(iofs) do { \
    __builtin_amdgcn_s_setprio(1); \
    _Pragma("unroll") \
    for (int ii = 0; ii < 4; ++ii) { \
        _Pragma("unroll") \
        for (int jj = 0; jj < 2; ++jj) { \
            acc[(iofs) + ii][jj] = __builtin_amdgcn_mfma_f32_16x16x32_bf16( \
                aF[((iofs) + ii) * 2 + 0], bL[jj * 2 + 0], acc[(iofs) + ii][jj], 0, 0, 0); \
            acc[(iofs) + ii][jj] = __builtin_amdgcn_mfma_f32_16x16x32_bf16( \
                aF[((iofs) + ii) * 2 + 1], bL[jj * 2 + 1], acc[(iofs) + ii][jj], 0, 0, 0); \
        } } \
    __builtin_amdgcn_s_setprio(0); \
} while (0)

template<int MODE>
__global__ __launch_bounds__(512, 2) void gemm4p(
    const unsigned short* __restrict__ A,
    const unsigned short* __restrict__ B,
    const float* __restrict__ bias,
    float* __restrict__ Cf,
    unsigned short* __restrict__ q_ws,
    unsigned short* __restrict__ k_ws,
    unsigned short* __restrict__ vT_ws,
    int M, int N, int K)
{
    extern __shared__ char ldsc[];
    char* const bufc = ldsc;

    const int nby = M >> 8;
    const int nwg = gridDim.x;
    const int qq = nwg >> 3;
    const int wg = (blockIdx.x & 7) * qq + (blockIdx.x >> 3);
    const int by = wg % nby, bx = wg / nby;
    const int m0 = by << 8, n0 = bx << 7;

    const int tid = threadIdx.x;
    const int lane = tid & 63, wid = tid >> 6;
    const int li = lane & 15, quad = lane >> 4;
    const int wr = wid >> 2, wc = wid & 3;

    const int rstage = tid >> 3;
    const int scol = (((tid & 7) ^ ((tid >> 3) & 7)) << 3);
    const unsigned short* Ab = A + (size_t)m0 * K;
    const unsigned short* Bb = B + (size_t)n0 * K;

    const int swz = (lane & 7) << 4;
    const int ks0 = ((quad << 4)     ) ^ swz;
    const int ks1 = ((quad << 4) + 64) ^ swz;
    const int rdoffA = li * 128;
    const int rdoffB = li * 128 + ((wc & 1) << 12);

    const char* rdA0 = bufc + wr * 16384;
    const char* rdB0 = bufc + 32768 + (wc >> 1) * 8192;
    const char* rdA1 = rdA0 + 49152;
    const char* rdB1 = rdB0 + 49152;

    floatx4 acc[8][2] = {};
    bf16x8 aF[16], bL[4];

    const int KTn = K >> 6;

    STAGE_TILE(0, 0);
    STAGE_TILE(1, 1);
    VMCNT(6);
    BARF();

    for (int t = 0; t < KTn; t += 2) {
        const bool pf = (t + 2 < KTn);

        #pragma unroll
        for (int ii = 0; ii < 8; ++ii) { aF[ii*2+0] = RDA(rdA0, ii, ks0); aF[ii*2+1] = RDA(rdA0, ii, ks1); }
        #pragma unroll
        for (int jj = 0; jj < 2; ++jj) { bL[jj*2+0] = RDB(rdB0, jj, ks0); bL[jj*2+1] = RDB(rdB0, jj, ks1); }
        BARF();
        MFMA_C(0);
        LGKM0();
        BARF();

        if (pf) STAGE_TILE(0, t + 2);
        BARF();
        MFMA_C(4);
        if (pf) { VMCNT(6); } else { VMCNT(0); }
        BARF();

        #pragma unroll
        for (int ii = 0; ii < 8; ++ii) { aF[ii*2+0] = RDA(rdA1, ii, ks0); aF[ii*2+1] = RDA(rdA1, ii, ks1); }
        #pragma unroll
        for (int jj = 0; jj < 2; ++jj) { bL[jj*2+0] = RDB(rdB1, jj, ks0); bL[jj*2+1] = RDB(rdB1, jj, ks1); }
        BARF();
        MFMA_C(0);
        LGKM0();
        BARF();

        if (pf) STAGE_TILE(1, t + 3);
        BARF();
        MFMA_C(4);
        if (pf) { VMCNT(6); } else { VMCNT(0); }
        BARF();
    }

    const int colb = wc * 32;
    const int rowb = wr * 128;
    if (MODE == 0) {
        #pragma unroll
        for (int i2 = 0; i2 < 8; ++i2)
            #pragma unroll
            for (int j2 = 0; j2 < 2; ++j2) {
                const int col = n0 + colb + j2 * 16 + li;
                const float bv = bias[col];
                #pragma unroll
                for (int r = 0; r < 4; ++r) {
                    const int row = m0 + rowb + i2 * 16 + quad * 4 + r;
                    Cf[(size_t)row * N + col] = acc[i2][j2][r] + bv;
                }
            }
    } else {
        const int which = bx >> 4;           // 0:q 1:k 2:vT
        const int hh = bx & 15;
        const int lbase = m0 & 2047;
        const size_t bh = (size_t)((m0 >> 11) * 16 + hh);
        if (which == 2) {
            unsigned short (*Lv)[264] = (unsigned short(*)[264])ldsc;
            #pragma unroll
            for (int i2 = 0; i2 < 8; ++i2)
                #pragma unroll
                for (int j2 = 0; j2 < 2; ++j2) {
                    const int col = colb + j2 * 16 + li;
                    const float bv = bias[n0 + col];
                    #pragma unroll
                    for (int r = 0; r < 4; ++r) {
                        const int row = rowb + i2 * 16 + quad * 4 + r;
                        Lv[col][row] = f2bf(acc[i2][j2][r] + bv);
                    }
                }
            __syncthreads();
            #pragma unroll
            for (int c = 0; c < 8; ++c) {
                int chunk = c * 512 + tid;
                int d = chunk >> 5;
                int ls = (chunk & 31) * 8;
                *(uint4*)(vT_ws + (bh * 128 + d) * 2048 + lbase + ls) =
                    *(const uint4*)&Lv[d][ls];
            }
        } else {
            unsigned short (*Lq)[136] = (unsigned short(*)[136])ldsc;
            #pragma unroll
            for (int i2 = 0; i2 < 8; ++i2)
                #pragma unroll
                for (int j2 = 0; j2 < 2; ++j2) {
                    const int col = colb + j2 * 16 + li;
                    const float bv = bias[n0 + col];
                    #pragma unroll
                    for (int r = 0; r < 4; ++r) {
                        const int row = rowb + i2 * 16 + quad * 4 + r;
                        Lq[row][col] = f2bf(acc[i2][j2][r] + bv);
                    }
                }
            __syncthreads();
            unsigned short* dst = which ? k_ws : q_ws;
            #pragma unroll
            for (int c = 0; c < 8; ++c) {
                int chunk = c * 512 + tid;
                int row = chunk >> 4;
                int dc = (chunk & 15) * 8;
                *(uint4*)(dst + (bh * 2048 + lbase + row) * (size_t)128 + dc) =
                    *(const uint4*)&Lq[row][dc];
            }
        }
    }
}

// ---------------------------------------------------------------- attention
// Baseline structure (QBLK=128, KVBLK=128, 4 q-split waves, 512 blocks,
// balanced pairing) + PIPELINED global_load_lds staging:
//  - R6 counters showed WRITE_SIZE 270MB (vs 17MB output) => reg-staged K/V
//    (kr/vr[8] live across tile body) spills to scratch. gl_lds staging has
//    ZERO register footprint -> no spill possible.
//  - double-buffered LDS (2 x 64KB linear), counted VMCNT(16), raw s_barrier
//    only (never __syncthreads in the loop: it drains vmcnt(0)).
//  - T2 both-sides swizzle, 16-slot variant: cu ^= (row&15)<<3 (ushort) ->
//    32 lanes hit 16 distinct 16B slots = 2 lanes/bank = conflict-free.
//    Source pre-swizzle is a per-thread constant.
__global__ __launch_bounds__(256, 1) void attn_kernel(
    const unsigned short* __restrict__ q_ws,
    const unsigned short* __restrict__ k_ws,
    const unsigned short* __restrict__ vT_ws,
    unsigned short* __restrict__ aout,
    const int* __restrict__ causal_ptr)
{
    extern __shared__ char asmem[];
    // buf b (0/1) at b*65536: K [128][128] at +0 (32KB), V^T [128][128] at +32768

    // balanced mapping: blocks c and c+256 sum to 17 tile-computes
    const int ord = blockIdx.x;
    int qt, bhid;
    if (ord < 256) { qt = ord >> 5;              bhid = ord & 31; }
    else           { qt = 15 - ((ord - 256) >> 5); bhid = ord & 31; }
    const int b = bhid >> 4, h = bhid & 15;

    const int tid = threadIdx.x;
    const int lane = tid & 63, w = tid >> 6;       // 4 waves
    const int lq = lane & 31;                      // q-col / row-in-tile
    const int half = lane >> 5;
    const size_t bh = (size_t)(b * 16 + h);
    const unsigned short* Qp = q_ws + bh * 2048 * 128;
    const unsigned short* Kp = k_ws + bh * 2048 * 128;
    const unsigned short* Vp = vT_ws + bh * 128 * 2048;
    const int causal = causal_ptr[0];
    const float scale = 0.08838834764831845f;      // 1/sqrt(128)

    // staging constants: dest row = c*16 + (tid>>4), dest 16B slot = tid&15;
    // source col pre-swizzled so LDS stays linear (T2 both-sides rule)
    const int trow = tid >> 4;                               // 0..15
    const int sco  = (((tid & 15) ^ (tid >> 4)) << 3);       // swizzled src col (ushort)
    const int widB = (tid >> 6) * 1024;                      // wave-uniform dest part
    // read-side swizzle
    const int rsw = (lq & 15) << 3;

#define ATTN_STAGE(bsel, ktile) do { \
    char* _kd = asmem + (bsel) * 65536 + widB; \
    char* _vd = _kd + 32768; \
    const unsigned short* _ks = Kp + (size_t)((ktile) * 128 + trow) * 128 + sco; \
    const unsigned short* _vs = Vp + (size_t)trow * 2048 + (ktile) * 128 + sco; \
    _Pragma("unroll") \
    for (int _c = 0; _c < 8; ++_c) { \
        gl_lds16(_ks + (size_t)_c * 2048,  _kd + _c * 4096); \
        gl_lds16(_vs + (size_t)_c * 32768, _vd + _c * 4096); \
    } \
} while (0)   /* 16 vm-instructions */

    // Q^T B-operand frags (persist): qf[s][j] = Q[qg][16s + 8*half + j]
    const int qg = qt * 128 + w * 32 + lq;
    bf16x8 qf[8];
    #pragma unroll
    for (int s = 0; s < 8; ++s)
        qf[s] = *(const bf16x8*)(Qp + (size_t)qg * 128 + s * 16 + half * 8);

    floatx16 O[4] = {};
    float m_i = -INFINITY, l_i = 0.f;

    const int myEnd = causal ? qt : 15;

    // prologue: stage tile0 -> buf0, tile1 -> buf1 (if any); wait tile0 only
    ATTN_STAGE(0, 0);
    if (myEnd >= 1) { ATTN_STAGE(1, 1); VMCNT(16); }
    else            { VMCNT(0); }
    BARF();

    for (int kt = 0; kt <= myEnd; ++kt) {
        const unsigned short* Ksc = (const unsigned short*)(asmem + (kt & 1) * 65536);
        const unsigned short* Vsc = Ksc + 16384;

        // S^T[key][q]: 4 key-groups of 32; A = K rows, B = Q^T
        floatx16 S[4] = {};
        #pragma unroll
        for (int ct = 0; ct < 4; ++ct)
            #pragma unroll
            for (int s = 0; s < 8; ++s) {
                bf16x8 kf = *(const bf16x8*)(Ksc + (ct * 32 + lq) * 128 + ((s * 16 + half * 8) ^ rsw));
                S[ct] = __builtin_amdgcn_mfma_f32_32x32x16_bf16(kf, qf[s], S[ct], 0, 0, 0);
            }

        // scale + causal mask; row stats are LANE-LOCAL (col of S^T = q)
        const bool diag = causal && (kt == qt);
        float mx = -INFINITY;
        #pragma unroll
        for (int ct = 0; ct < 4; ++ct)
            #pragma unroll
            for (int r = 0; r < 16; ++r) {
                float sv = S[ct][r] * scale;
                if (diag) {
                    int key = 32 * ct + (r & 3) + 8 * (r >> 2) + 4 * half;
                    if (kt * 128 + key > qg) sv = -INFINITY;
                }
                S[ct][r] = sv;
                mx = fmaxf(mx, sv);
            }
        mx = fmaxf(mx, __shfl_xor(mx, 32, 64));   // combine key-halves
        float m_new = fmaxf(m_i, mx);
        float m_use = (m_new == -INFINITY) ? 0.f : m_new;
        float alpha = __expf(m_i - m_use);

        float rs = 0.f;
        #pragma unroll
        for (int ct = 0; ct < 4; ++ct)
            #pragma unroll
            for (int r = 0; r < 16; ++r) {
                float p = __expf(S[ct][r] - m_use);
                S[ct][r] = p;
                rs += p;
            }
        rs += __shfl_xor(rs, 32, 64);
        l_i = l_i * alpha + rs;
        m_i = m_new;
        #pragma unroll
        for (int dt = 0; dt < 4; ++dt)
            #pragma unroll
            for (int r = 0; r < 16; ++r)
                O[dt][r] *= alpha;

        // P^T -> B-operand frags via register half-swap (no LDS round-trip)
        bf16x8 pfr[8];
        #pragma unroll
        for (int ct = 0; ct < 4; ++ct)
            #pragma unroll
            for (int h2 = 0; h2 < 2; ++h2) {
                int base = 8 * h2;
                unsigned int pk0 = pkbf(S[ct][base + 0], S[ct][base + 1]);
                unsigned int pk1 = pkbf(S[ct][base + 2], S[ct][base + 3]);
                unsigned int pk2 = pkbf(S[ct][base + 4], S[ct][base + 5]);
                unsigned int pk3 = pkbf(S[ct][base + 6], S[ct][base + 7]);
                unsigned int x0 = __shfl_xor((int)pk0, 32, 64);
                unsigned int x1 = __shfl_xor((int)pk1, 32, 64);
                unsigned int x2 = __shfl_xor((int)pk2, 32, 64);
                unsigned int x3 = __shfl_xor((int)pk3, 32, 64);
                union { unsigned int u[4]; bf16x8 v; } fr;
                fr.u[0] = half ? x2 : pk0;
                fr.u[1] = half ? x3 : pk1;
                fr.u[2] = half ? pk2 : x0;
                fr.u[3] = half ? pk3 : x1;
                pfr[ct * 2 + h2] = fr.v;
            }

        // O^T[d][q] += V^T * P^T; A = V^T rows (d), B = pfr
        #pragma unroll
        for (int dt = 0; dt < 4; ++dt)
            #pragma unroll
            for (int s = 0; s < 8; ++s) {
                bf16x8 vf = *(const bf16x8*)(Vsc + (dt * 32 + lq) * 128 + ((s * 16 + half * 8) ^ rsw));
                O[dt] = __builtin_amdgcn_mfma_f32_32x32x16_bf16(vf, pfr[s], O[dt], 0, 0, 0);
            }

        // all this wave's LDS reads are retired (consumed by MFMAs above)
        BARF();                              // every wave done reading buf[kt&1]
        if (kt + 2 <= myEnd) {
            ATTN_STAGE(kt & 1, kt + 2);      // overwrite the buffer just freed
            VMCNT(16);                       // tile kt+1 fully arrived
        } else {
            VMCNT(0);
        }
        BARF();                              // buf[(kt+1)&1] visible to all
    }

    // epilogue: normalize, transpose O^T->[q][d] via padded Ep, store
    unsigned short* const Ep = (unsigned short*)asmem;   // [128][136] padded
    const float invl = 1.0f / l_i;
    #pragma unroll
    for (int dt = 0; dt < 4; ++dt)
        #pragma unroll
        for (int g = 0; g < 4; ++g) {
            int dbase = dt * 32 + g * 8 + half * 4;
            ushort4 o4;
            o4.x = f2bf(O[dt][g * 4 + 0] * invl);
            o4.y = f2bf(O[dt][g * 4 + 1] * invl);
            o4.z = f2bf(O[dt][g * 4 + 2] * invl);
            o4.w = f2bf(O[dt][g * 4 + 3] * invl);
            *(ushort4*)(Ep + (w * 32 + lq) * 136 + dbase) = o4;
        }
    __syncthreads();
    #pragma unroll
    for (int c = 0; c < 8; ++c) {
        int chunk = c * 256 + tid;                // 0..2047
        int row = chunk >> 4;                     // 0..127 (q within tile)
        int dc = (chunk & 15) * 8;
        uint4 v = *(const uint4*)(Ep + row * 136 + dc);
        *(uint4*)(aout + ((size_t)b * 2048 + qt * 128 + row) * 2048 + h * 128 + dc) = v;
    }
#undef ATTN_STAGE
}

// ---------------------------------------------------------------- launch
extern "C" void kernel_launch(void* const* d_in, const int* in_sizes, int n_in,
                              void* d_out, int out_size, void* d_ws, size_t ws_size,
                              hipStream_t stream) {
    const float* x     = (const float*)d_in[0];
    const float* w_in  = (const float*)d_in[1];
    const float* b_in  = (const float*)d_in[2];
    const float* w_out = (const float*)d_in[3];
    const float* b_out = (const float*)d_in[4];
    const int* causal  = (const int*)d_in[5];

    char* ws = (char*)d_ws;
    unsigned short* xb    = (unsigned short*)ws; ws += (size_t)4096 * 2048 * 2;
    unsigned short* wb    = (unsigned short*)ws; ws += (size_t)6144 * 2048 * 2;
    unsigned short* wob   = (unsigned short*)ws; ws += (size_t)2048 * 2048 * 2;
    unsigned short* q_ws  = (unsigned short*)ws; ws += (size_t)32 * 2048 * 128 * 2;
    unsigned short* k_ws  = (unsigned short*)ws; ws += (size_t)32 * 2048 * 128 * 2;
    unsigned short* vT_ws = (unsigned short*)ws; ws += (size_t)32 * 2048 * 128 * 2;
    unsigned short* aout  = (unsigned short*)ws; ws += (size_t)4096 * 2048 * 2;

    static int once = []() {
        auto* f0 = gemm4p<0>;
        auto* f1 = gemm4p<1>;
        hipFuncSetAttribute((const void*)f0,
            hipFuncAttributeMaxDynamicSharedMemorySize, 98304);
        hipFuncSetAttribute((const void*)f1,
            hipFuncAttributeMaxDynamicSharedMemorySize, 98304);
        hipFuncSetAttribute((const void*)attn_kernel,
            hipFuncAttributeMaxDynamicSharedMemorySize, 131072);
        return 0;
    }();
    (void)once;

    cast_f32_bf16<<<8192, 256, 0, stream>>>(x, xb, 4096 * 2048);
    cast_f32_bf16<<<12288, 256, 0, stream>>>(w_in, wb, 6144 * 2048);
    cast_f32_bf16<<<4096, 256, 0, stream>>>(w_out, wob, 2048 * 2048);

    // QKV: M=4096, N=6144 -> grid 16*48 = 768 = 3 full rounds
    gemm4p<1><<<768, 512, 98304, stream>>>(
        xb, wb, b_in, nullptr, q_ws, k_ws, vT_ws, 4096, 6144, 2048);

    // attn: 512 blocks (balanced pairing), 131,072 B dynamic LDS (dbuf)
    attn_kernel<<<512, 256, 131072, stream>>>(
        q_ws, k_ws, vT_ws, aout, causal);

    // out-proj: M=4096, N=2048 -> grid 16*16 = 256 = 1 full round
    gemm4p<0><<<256, 512, 98304, stream>>>(
        aout, wob, b_out, (float*)d_out, nullptr, nullptr, nullptr,
        4096, 2048, 2048);
}